// Round 3
// baseline (123.969 us; speedup 1.0000x reference)
//
#include <hip/hip_runtime.h>
#include <hip/hip_bf16.h>

#define B_DIM 16384
#define P_DIM 4096
#define D_DIM 256
#define BK 64

typedef float f32x4 __attribute__((ext_vector_type(4)));
typedef __bf16 bf16x8 __attribute__((ext_vector_type(8)));

__device__ __forceinline__ unsigned short f2bf_rne(float f) {
  unsigned int u = __builtin_bit_cast(unsigned int, f);
  u += 0x7fffu + ((u >> 16) & 1u);
  return (unsigned short)(u >> 16);
}

// One wave per row: fp32 -> bf16 conversion + fp32 sum-of-squares.
__global__ __launch_bounds__(256) void prep_kernel(
    const float* __restrict__ x, const float* __restrict__ p,
    unsigned short* __restrict__ xb, unsigned short* __restrict__ pb,
    float* __restrict__ xsq, float* __restrict__ psq) {
  int row  = blockIdx.x * 4 + (threadIdx.x >> 6);
  int lane = threadIdx.x & 63;
  const float4* src;
  unsigned short* dst;
  float* sq;
  if (row < B_DIM) {
    src = (const float4*)(x + (size_t)row * D_DIM);
    dst = xb + (size_t)row * D_DIM;
    sq  = xsq + row;
  } else {
    int r = row - B_DIM;
    src = (const float4*)(p + (size_t)r * D_DIM);
    dst = pb + (size_t)r * D_DIM;
    sq  = psq + r;
  }
  float4 v = src[lane];
  ushort4 o;
  o.x = f2bf_rne(v.x); o.y = f2bf_rne(v.y);
  o.z = f2bf_rne(v.z); o.w = f2bf_rne(v.w);
  ((ushort4*)dst)[lane] = o;
  float s = v.x * v.x + v.y * v.y + v.z * v.z + v.w * v.w;
  #pragma unroll
  for (int off = 32; off > 0; off >>= 1) s += __shfl_down(s, off);
  if (lane == 0) *sq = s;
}

__device__ __forceinline__ void async16(const unsigned short* g, void* l) {
  __builtin_amdgcn_global_load_lds(
      (const __attribute__((address_space(1))) void*)g,
      (__attribute__((address_space(3))) void*)l,
      16, 0, 0);
}

// Persistent GEMM: 1024 blocks (4/CU), each does 4 output tiles (same bn,
// bm advances by 4). Single-buffered 32 KB LDS, BK=64. Epilogue transposes
// acc through the wave-private staging quarter -> dwordx4 nontemporal stores
// that stay in flight across the next generation's K-loop (counted vmcnt).
__global__ __launch_bounds__(256, 4) void dist_gemm(
    const unsigned short* __restrict__ A,   // [B_DIM][D_DIM] bf16 bits
    const unsigned short* __restrict__ Bm,  // [P_DIM][D_DIM] bf16 bits
    const float* __restrict__ xsq, const float* __restrict__ psq,
    float* __restrict__ out) {
  __shared__ __align__(16) char lds[32768];  // [0,16K)=A tile, [16K,32K)=B tile

  const int tid  = threadIdx.x;
  const int w    = tid >> 6;
  const int lane = tid & 63;
  const int bid  = blockIdx.x;

  const int wr = w >> 1, wc = w & 1;

  // Staging geometry (per-lane, same every tile). XOR swizzle on the GLOBAL
  // source (rule 21: gload_lds dest is linear); read side applies same XOR.
  const int q0 = w * 4096 + lane * 16;          // byte within 16 KB tile
  const int r0 = q0 >> 7;                       // row 0..127 (w*32 + lane>>3)
  const int cbyte = (q0 & 127) ^ ((r0 & 7) << 4);
  const int ce = cbyte >> 1;                    // element col 0..63

  // Fragment read geometry (verified R1/R2).
  const int ar   = wr * 64 + (lane & 15);
  const int br   = wc * 64 + (lane & 15);
  const int xr   = (lane & 7) << 4;
  const int kcol = (lane >> 4) * 16;

  // Tile mapping: vb = bid + g*1024; swz = (vb&7)*512 + vb>>3 (bijective).
  // bn constant across g (B panel L2-hot); bm = bm0 + 4g.
  const int swz0 = (bid & 7) * 512 + (bid >> 3);
  const int bn   = swz0 & 31;
  const int bm0  = swz0 >> 5;

  const char* La = lds;
  const char* Lb = lds + 16384;

  const unsigned short* Abase = A  + (size_t)r0 * D_DIM + ce;
  const unsigned short* Bbase = Bm + (size_t)(bn * 128 + r0) * D_DIM + ce;

#define STAGE_A(bm_, kt_) do { _Pragma("unroll")                               \
    for (int l = 0; l < 4; ++l)                                                \
      async16(Abase + ((size_t)(bm_) * 128 + 8 * l) * D_DIM + (kt_),           \
              (void*)(lds + w * 4096 + l * 1024)); } while (0)
#define STAGE_B(kt_) do { _Pragma("unroll")                                    \
    for (int l = 0; l < 4; ++l)                                                \
      async16(Bbase + (size_t)(8 * l) * D_DIM + (kt_),                         \
              (void*)(lds + 16384 + w * 4096 + l * 1024)); } while (0)

  // Prologue: stage gen-0 tile 0.
  STAGE_A(bm0, 0);
  STAGE_B(0);
  asm volatile("s_waitcnt vmcnt(0)" ::: "memory");
  __builtin_amdgcn_s_barrier();
  __builtin_amdgcn_sched_barrier(0);

  #pragma unroll 1
  for (int g = 0; g < 4; ++g) {
    const int bm = bm0 + g * 4;

    f32x4 acc[4][4];
    #pragma unroll
    for (int m = 0; m < 4; ++m)
      #pragma unroll
      for (int n = 0; n < 4; ++n) acc[m][n] = 0.0f;

    #pragma unroll
    for (int t = 0; t < 4; ++t) {
      #pragma unroll
      for (int qk = 0; qk < 2; ++qk) {
        bf16x8 av[4], bv[4];
        #pragma unroll
        for (int m = 0; m < 4; ++m)
          av[m] = *(const bf16x8*)(La + (ar + m * 16) * 128 + ((kcol + qk * 64) ^ xr));
        #pragma unroll
        for (int n = 0; n < 4; ++n)
          bv[n] = *(const bf16x8*)(Lb + (br + n * 16) * 128 + ((kcol + qk * 64) ^ xr));
        #pragma unroll
        for (int m = 0; m < 4; ++m)
          #pragma unroll
          for (int n = 0; n < 4; ++n)
            acc[m][n] = __builtin_amdgcn_mfma_f32_16x16x32_bf16(av[m], bv[n], acc[m][n], 0, 0, 0);
      }
      __builtin_amdgcn_sched_barrier(0);
      __builtin_amdgcn_s_barrier();       // all waves done reading this tile
      __builtin_amdgcn_sched_barrier(0);
      if (t < 3) {
        STAGE_A(bm, (t + 1) * BK);
        STAGE_B((t + 1) * BK);
        asm volatile("s_waitcnt vmcnt(0)" ::: "memory");
        __builtin_amdgcn_s_barrier();
        __builtin_amdgcn_sched_barrier(0);
      }
    }

    // ---- Epilogue: transpose 64x64 wave tile via own 4 KB quarter ----
    const int rowbase = bm * 128 + wr * 64;
    const int colbase = bn * 128 + wc * 64;
    float* scr = (float*)(lds + w * 4096);    // wave-private (A quarter)

    if (g < 3) STAGE_B(0);                    // next gen B tile (B quarter free)

    const int rr  = lane >> 2;
    const int cbk = lane & 3;
    #pragma unroll
    for (int m = 0; m < 4; ++m) {
      #pragma unroll
      for (int n = 0; n < 4; ++n) {
        const float ps = psq[colbase + n * 16 + (lane & 15)];
        #pragma unroll
        for (int j = 0; j < 4; ++j) {
          const int lr = (lane >> 4) * 4 + j;
          const float xs = xsq[rowbase + m * 16 + lr];
          float v = fmaf(-2.0f, acc[m][n][j], xs + ps);
          v = __builtin_sqrtf(fmaxf(v, 0.0f));
          const int lc = n * 16 + (lane & 15);
          scr[lr * 64 + (lc ^ ((lr & 7) << 2))] = v;
        }
      }
      asm volatile("s_waitcnt lgkmcnt(0)" ::: "memory");
      __builtin_amdgcn_sched_barrier(0);
      f32x4 vv[4];
      #pragma unroll
      for (int i = 0; i < 4; ++i) {
        const int col4 = cbk * 4 + i * 16;
        vv[i] = *(const f32x4*)&scr[rr * 64 + (col4 ^ ((rr & 7) << 2))];
      }
      if (m == 3 && g < 3) {
        // pass-3 reads retired -> safe to overwrite A quarter with next tile
        asm volatile("s_waitcnt lgkmcnt(0)" ::: "memory");
        __builtin_amdgcn_sched_barrier(0);
        STAGE_A(bm + 4, 0);
        __builtin_amdgcn_sched_barrier(0);
      }
      #pragma unroll
      for (int i = 0; i < 4; ++i) {
        const int col4 = cbk * 4 + i * 16;
        __builtin_nontemporal_store(
            vv[i], (f32x4*)&out[(size_t)(rowbase + m * 16 + rr) * P_DIM + colbase + col4]);
      }
    }

    if (g < 3) {
      // Issue order: STAGE_B(4), 12 stores, STAGE_A(4), 4 stores.
      // vmcnt(4): all but the 4 newest (stores) done => both stages landed,
      // WITHOUT draining the store stream.
      asm volatile("s_waitcnt vmcnt(4)" ::: "memory");
      __builtin_amdgcn_s_barrier();
      __builtin_amdgcn_sched_barrier(0);
    }
  }
#undef STAGE_A
#undef STAGE_B
}

extern "C" void kernel_launch(void* const* d_in, const int* in_sizes, int n_in,
                              void* d_out, int out_size, void* d_ws, size_t ws_size,
                              hipStream_t stream) {
  const float* x = (const float*)d_in[0];
  const float* p = (const float*)d_in[1];
  float* out = (float*)d_out;

  char* ws = (char*)d_ws;
  unsigned short* xb = (unsigned short*)ws;                                // 8 MB
  unsigned short* pb = (unsigned short*)(ws + (size_t)B_DIM * D_DIM * 2);  // 2 MB
  float* xsq = (float*)(ws + (size_t)(B_DIM + P_DIM) * D_DIM * 2);
  float* psq = xsq + B_DIM;

  prep_kernel<<<(B_DIM + P_DIM) / 4, 256, 0, stream>>>(x, p, xb, pb, xsq, psq);

  dist_gemm<<<1024, 256, 0, stream>>>(xb, pb, xsq, psq, out);
}

// Round 4
// 87.291 us; speedup vs baseline: 1.4202x; 1.4202x over previous
//
#include <hip/hip_runtime.h>
#include <hip/hip_bf16.h>

#define B_DIM 16384
#define P_DIM 4096
#define D_DIM 256
#define BK 64
#define NGEN 8
#define GRID 512

typedef float f32x4 __attribute__((ext_vector_type(4)));
typedef __bf16 bf16x8 __attribute__((ext_vector_type(8)));

__device__ __forceinline__ unsigned short f2bf_rne(float f) {
  unsigned int u = __builtin_bit_cast(unsigned int, f);
  u += 0x7fffu + ((u >> 16) & 1u);
  return (unsigned short)(u >> 16);
}

// One wave per row: fp32 -> bf16 conversion + fp32 sum-of-squares.
__global__ __launch_bounds__(256) void prep_kernel(
    const float* __restrict__ x, const float* __restrict__ p,
    unsigned short* __restrict__ xb, unsigned short* __restrict__ pb,
    float* __restrict__ xsq, float* __restrict__ psq) {
  int row  = blockIdx.x * 4 + (threadIdx.x >> 6);
  int lane = threadIdx.x & 63;
  const float4* src;
  unsigned short* dst;
  float* sq;
  if (row < B_DIM) {
    src = (const float4*)(x + (size_t)row * D_DIM);
    dst = xb + (size_t)row * D_DIM;
    sq  = xsq + row;
  } else {
    int r = row - B_DIM;
    src = (const float4*)(p + (size_t)r * D_DIM);
    dst = pb + (size_t)r * D_DIM;
    sq  = psq + r;
  }
  float4 v = src[lane];
  ushort4 o;
  o.x = f2bf_rne(v.x); o.y = f2bf_rne(v.y);
  o.z = f2bf_rne(v.z); o.w = f2bf_rne(v.w);
  ((ushort4*)dst)[lane] = o;
  float s = v.x * v.x + v.y * v.y + v.z * v.z + v.w * v.w;
  #pragma unroll
  for (int off = 32; off > 0; off >>= 1) s += __shfl_down(s, off);
  if (lane == 0) *sq = s;
}

__device__ __forceinline__ void async16(const unsigned short* g, void* l) {
  __builtin_amdgcn_global_load_lds(
      (const __attribute__((address_space(1))) void*)g,
      (__attribute__((address_space(3))) void*)l,
      16, 0, 0);
}

// Persistent store-paced GEMM: 512 blocks (2/CU), 8 gens each. Dbuf K-loop
// (BK=64, 4 steps/gen); prev gen's 64 output values drip out 16 stores per
// K-step with counted vmcnt(16) so the HBM write stream never drains.
__global__ __launch_bounds__(256, 2) void dist_gemm(
    const unsigned short* __restrict__ A,   // [B_DIM][D_DIM] bf16 bits
    const unsigned short* __restrict__ Bm,  // [P_DIM][D_DIM] bf16 bits
    const float* __restrict__ xsq, const float* __restrict__ psq,
    float* __restrict__ out) {
  __shared__ __align__(16) char lds[2][2][16384];  // [buf][A|B][16 KB]

  const int tid  = threadIdx.x;
  const int w    = tid >> 6;
  const int lane = tid & 63;
  const int bid  = blockIdx.x;
  const int wr = w >> 1, wc = w & 1;

  // Tile map: v = bid + 512g; swz = (v&7)*512 + v>>3 (bijective).
  // => bn constant per block, bm = bm_base + 2g. XCD keeps B panel L2-hot.
  const int swz0    = (bid & 7) * 512 + (bid >> 3);
  const int bn      = swz0 & 31;
  const int bm_base = swz0 >> 5;

  // Staging geometry (rule 21: linear LDS dest, pre-swizzled global source).
  const int q0 = w * 4096 + lane * 16;
  const int r0 = q0 >> 7;                       // w*32 + (lane>>3)
  const int ce = ((q0 & 127) ^ ((r0 & 7) << 4)) >> 1;
  const unsigned short* Acol = A  + (size_t)r0 * D_DIM + ce;
  const unsigned short* Bcol = Bm + (size_t)(bn * 128 + r0) * D_DIM + ce;

  // Fragment read geometry (verified R1-R3).
  const int ar   = wr * 64 + (lane & 15);
  const int br   = wc * 64 + (lane & 15);
  const int xr   = (lane & 7) << 4;
  const int kcol = (lane >> 4) * 16;

  const int colb_lane = bn * 128 + wc * 64 + (lane & 15);
  float psv[4];
  #pragma unroll
  for (int n = 0; n < 4; ++n) psv[n] = psq[colb_lane + n * 16];

  f32x4 acc[4][4];
  #pragma unroll
  for (int m = 0; m < 4; ++m)
    #pragma unroll
    for (int n = 0; n < 4; ++n) acc[m][n] = 0.0f;
  float pend[4][4][4];   // finished values of previous gen (static idx only)
  f32x4 xs4[4];
  size_t pobase = 0;

#define STAGE_AB(bufi, nbm, nkt) do { _Pragma("unroll")                        \
    for (int l = 0; l < 4; ++l) {                                              \
      async16(Acol + ((size_t)((nbm) * 128 + 8 * l)) * D_DIM + (nkt),          \
              (void*)(&lds[bufi][0][0] + w * 4096 + l * 1024));                \
      async16(Bcol + (size_t)(8 * l) * D_DIM + (nkt),                          \
              (void*)(&lds[bufi][1][0] + w * 4096 + l * 1024));                \
    } } while (0)

  // Prologue: stage gen0 k-tile 0 into buf0.
  STAGE_AB(0, bm_base, 0);
  asm volatile("s_waitcnt vmcnt(0)" ::: "memory");
  __builtin_amdgcn_s_barrier();
  __builtin_amdgcn_sched_barrier(0);

  #pragma unroll 1
  for (int g = 0; g < NGEN; ++g) {
    const int bmg  = bm_base + 2 * g;
    const int rowb = bmg * 128 + wr * 64 + ((lane >> 4) << 2);

    #pragma unroll
    for (int t = 0; t < 4; ++t) {
      // ---- phase 1: stage next K-tile (oldest VMEM this step) ----
      const int s = g * 4 + t + 1;
      if (s < NGEN * 4) {
        const int nbm = bm_base + 2 * (s >> 2);
        const int nkt = (s & 3) * BK;
        if ((t & 1) == 0) STAGE_AB(1, nbm, nkt); else STAGE_AB(0, nbm, nkt);
      }
      __builtin_amdgcn_sched_barrier(0);
      // ---- phase 2: 16 stores of previous gen's tile ----
      if (g > 0) {
        #pragma unroll
        for (int j = 0; j < 4; ++j)
          #pragma unroll
          for (int n = 0; n < 4; ++n)
            __builtin_nontemporal_store(pend[t][n][j],
                out + pobase + (size_t)((t * 16 + j) * P_DIM + n * 16));
      }
      __builtin_amdgcn_sched_barrier(0);
      // ---- phase 3 (t==2): row norms for this gen (newest 4 VMEM) ----
      if (t == 2) {
        #pragma unroll
        for (int m = 0; m < 4; ++m)
          xs4[m] = *(const f32x4*)(xsq + rowb + m * 16);
      }
      __builtin_amdgcn_sched_barrier(0);
      // ---- phase 4: 32 MFMA on current buf (t&1) ----
      {
        const char* La = &lds[t & 1][0][0];
        const char* Lb = &lds[t & 1][1][0];
        #pragma unroll
        for (int qk = 0; qk < 2; ++qk) {
          bf16x8 av[4], bv[4];
          #pragma unroll
          for (int m = 0; m < 4; ++m)
            av[m] = *(const bf16x8*)(La + (ar + m * 16) * 128 + ((kcol + qk * 64) ^ xr));
          #pragma unroll
          for (int n = 0; n < 4; ++n)
            bv[n] = *(const bf16x8*)(Lb + (br + n * 16) * 128 + ((kcol + qk * 64) ^ xr));
          #pragma unroll
          for (int m = 0; m < 4; ++m)
            #pragma unroll
            for (int n = 0; n < 4; ++n)
              acc[m][n] = __builtin_amdgcn_mfma_f32_16x16x32_bf16(av[m], bv[n], acc[m][n], 0, 0, 0);
        }
      }
      __builtin_amdgcn_sched_barrier(0);
      // ---- phase 5: counted wait (stage retired, stores stay in flight) ----
      if (g == 0) {
        if (t == 2) asm volatile("s_waitcnt vmcnt(4)" ::: "memory");
        else        asm volatile("s_waitcnt vmcnt(0)" ::: "memory");
      } else {
        asm volatile("s_waitcnt vmcnt(16)" ::: "memory");
      }
      __builtin_amdgcn_s_barrier();
      __builtin_amdgcn_sched_barrier(0);
    }

    // ---- gen epilogue: fold norms, sqrt, park in pend; reset acc ----
    #pragma unroll
    for (int m = 0; m < 4; ++m)
      #pragma unroll
      for (int n = 0; n < 4; ++n)
        #pragma unroll
        for (int j = 0; j < 4; ++j) {
          float v = fmaf(-2.0f, acc[m][n][j], xs4[m][j] + psv[n]);
          pend[m][n][j] = __builtin_sqrtf(fmaxf(v, 0.0f));
          acc[m][n][j] = 0.0f;
        }
    pobase = (size_t)rowb * P_DIM + (size_t)colb_lane;
  }

  // Final drain: last gen's 64 stores (retire at kernel end).
  #pragma unroll
  for (int m = 0; m < 4; ++m)
    #pragma unroll
    for (int j = 0; j < 4; ++j)
      #pragma unroll
      for (int n = 0; n < 4; ++n)
        __builtin_nontemporal_store(pend[m][n][j],
            out + pobase + (size_t)((m * 16 + j) * P_DIM + n * 16));
#undef STAGE_AB
}

extern "C" void kernel_launch(void* const* d_in, const int* in_sizes, int n_in,
                              void* d_out, int out_size, void* d_ws, size_t ws_size,
                              hipStream_t stream) {
  const float* x = (const float*)d_in[0];
  const float* p = (const float*)d_in[1];
  float* out = (float*)d_out;

  char* ws = (char*)d_ws;
  unsigned short* xb = (unsigned short*)ws;                                // 8 MB
  unsigned short* pb = (unsigned short*)(ws + (size_t)B_DIM * D_DIM * 2);  // 2 MB
  float* xsq = (float*)(ws + (size_t)(B_DIM + P_DIM) * D_DIM * 2);
  float* psq = xsq + B_DIM;

  prep_kernel<<<(B_DIM + P_DIM) / 4, 256, 0, stream>>>(x, p, xb, pb, xsq, psq);

  dist_gemm<<<GRID, 256, 0, stream>>>(xb, pb, xsq, psq, out);
}